// Round 1
// baseline (214.565 us; speedup 1.0000x reference)
//
#include <hip/hip_runtime.h>
#include <stdint.h>

typedef unsigned short u16;
typedef __attribute__((ext_vector_type(8))) __bf16 bf16x8;
typedef __attribute__((ext_vector_type(8))) short short8;
typedef __attribute__((ext_vector_type(4))) float f32x4;

#define N_NODES 4096
#define DMODEL  512   // 8 heads * 64
#define KD      64
#define NH      8

static __device__ __forceinline__ u16 f2bf(float f) {
  unsigned u = __builtin_bit_cast(unsigned, f);
  u += 0x7fffu + ((u >> 16) & 1u);
  return (u16)(u >> 16);
}

static __device__ __forceinline__ f32x4 mfma16(short8 a, short8 b, f32x4 c) {
  return __builtin_amdgcn_mfma_f32_16x16x32_bf16(
      __builtin_bit_cast(bf16x8, a), __builtin_bit_cast(bf16x8, b), c, 0, 0, 0);
}

// ---------------- prep kernels ----------------

__global__ void conv_bf16(const float* __restrict__ in, u16* __restrict__ out, int n4) {
  int i = blockIdx.x * blockDim.x + threadIdx.x;
  if (i < n4) {
    float4 v = ((const float4*)in)[i];
    u16 a = f2bf(v.x), b = f2bf(v.y), c = f2bf(v.z), d = f2bf(v.w);
    ushort4 o; o.x = a; o.y = b; o.z = c; o.w = d;
    ((ushort4*)out)[i] = o;
  }
}

// W[h][512][64] -> Wt[h*64+k][512] (transposed per head), optional scale
__global__ void pack_qkv(const float* __restrict__ Wk, const float* __restrict__ Wq,
                         const float* __restrict__ Wv, u16* __restrict__ Wkt,
                         u16* __restrict__ Wqt, u16* __restrict__ Wvt) {
  __shared__ float t[64][65];
  int z = blockIdx.z;            // mat*8 + h
  int mat = z >> 3, h = z & 7;
  const float* src = (mat == 0) ? Wk : ((mat == 1) ? Wq : Wv);
  u16* dst = (mat == 0) ? Wkt : ((mat == 1) ? Wqt : Wvt);
  float scale = (mat == 1) ? 0.125f : 1.0f;   // fold 1/sqrt(64) into Q
  src += (size_t)h * DMODEL * KD;
  dst += (size_t)h * KD * DMODEL;
  int r0 = blockIdx.x * 64;      // j tile
  int tid = threadIdx.x, lc = tid & 63;
#pragma unroll
  for (int i = 0; i < 16; ++i) {
    int row = i * 4 + (tid >> 6);
    t[row][lc] = src[(size_t)(r0 + row) * KD + lc];
  }
  __syncthreads();
#pragma unroll
  for (int i = 0; i < 16; ++i) {
    int row = i * 4 + (tid >> 6);   // k
    dst[(size_t)row * DMODEL + r0 + lc] = f2bf(t[lc][row] * scale);
  }
}

// Wo[512 c][512 o] -> Wot[o][c]
__global__ void pack_wo(const float* __restrict__ Wo, u16* __restrict__ Wot) {
  __shared__ float t[64][65];
  int r0 = blockIdx.x * 64, c0 = blockIdx.y * 64;
  int tid = threadIdx.x, lc = tid & 63;
#pragma unroll
  for (int i = 0; i < 16; ++i) {
    int row = i * 4 + (tid >> 6);
    t[row][lc] = Wo[(size_t)(r0 + row) * 512 + c0 + lc];
  }
  __syncthreads();
#pragma unroll
  for (int i = 0; i < 16; ++i) {
    int row = i * 4 + (tid >> 6);
    Wot[(size_t)(c0 + row) * 512 + r0 + lc] = f2bf(t[lc][row]);
  }
}

// adjacency (0/1 float, + self loops) -> bit matrix u64[4096][64]
__global__ void build_bits(const float* __restrict__ adj, unsigned long long* __restrict__ bits) {
  int gw = (blockIdx.x * blockDim.x + threadIdx.x) >> 6;
  int lane = threadIdx.x & 63;
  int nw = (gridDim.x * blockDim.x) >> 6;
  for (int word = gw; word < N_NODES * 64; word += nw) {
    int q = word >> 6, wc = word & 63;
    int k = wc * 64 + lane;
    float v = adj[(size_t)q * N_NODES + k];
    unsigned long long m = __ballot((v != 0.0f) || (q == k));
    if (lane == 0) bits[word] = m;
  }
}

// Vc[4096][512] -> Vt[h*64+d][4096]
__global__ void vtrans(const u16* __restrict__ Vc, u16* __restrict__ Vt) {
  __shared__ u16 t[64][65];
  int n0 = blockIdx.x * 64, h = blockIdx.y;
  int tid = threadIdx.x, lc = tid & 63;
#pragma unroll
  for (int i = 0; i < 16; ++i) {
    int row = i * 4 + (tid >> 6);
    t[row][lc] = Vc[(size_t)(n0 + row) * DMODEL + h * 64 + lc];
  }
  __syncthreads();
#pragma unroll
  for (int i = 0; i < 16; ++i) {
    int d = i * 4 + (tid >> 6);
    Vt[((size_t)h * 64 + d) * N_NODES + n0 + lc] = t[lc][d];
  }
}

// ---------------- GEMM: C[M][N] = A[M][K] * Bt[N][K]^T ----------------
// 64x64 tile / block, 4 waves, 16x16x32 bf16 MFMA, XOR-swizzled LDS.
template <bool OUT_BF16>
__global__ __launch_bounds__(256) void gemm_nt(const u16* __restrict__ A,
                                               const u16* __restrict__ Bt,
                                               void* __restrict__ C, int K,
                                               int lda, int ldb, int ldc) {
  __shared__ __align__(16) u16 lA[64 * 64];
  __shared__ __align__(16) u16 lB[64 * 64];
  const int m0 = blockIdx.x * 64, n0 = blockIdx.y * 64;
  const int tid = threadIdx.x;
  const int w = tid >> 6, lane = tid & 63, lm = lane & 15, lg = lane >> 4;
  const int srow = tid >> 2, sc0 = tid & 3;
  f32x4 acc[4] = {};
  for (int k0 = 0; k0 < K; k0 += 64) {
    __syncthreads();
    {
      const short8* ga = (const short8*)(A + (size_t)(m0 + srow) * lda + k0);
      short8* la = (short8*)(lA + srow * 64);
      la[sc0 ^ (srow & 7)] = ga[sc0];
      la[(sc0 + 4) ^ (srow & 7)] = ga[sc0 + 4];
      const short8* gb = (const short8*)(Bt + (size_t)(n0 + srow) * ldb + k0);
      short8* lb = (short8*)(lB + srow * 64);
      lb[sc0 ^ (srow & 7)] = gb[sc0];
      lb[(sc0 + 4) ^ (srow & 7)] = gb[sc0 + 4];
    }
    __syncthreads();
    short8 af0, af1;
    {
      int row = w * 16 + lm;
      af0 = ((short8*)(lA + row * 64))[lg ^ (row & 7)];
      af1 = ((short8*)(lA + row * 64))[(4 + lg) ^ (row & 7)];
    }
#pragma unroll
    for (int nt = 0; nt < 4; ++nt) {
      int row = nt * 16 + lm;
      short8 b0 = ((short8*)(lB + row * 64))[lg ^ (row & 7)];
      short8 b1 = ((short8*)(lB + row * 64))[(4 + lg) ^ (row & 7)];
      acc[nt] = mfma16(af0, b0, acc[nt]);
      acc[nt] = mfma16(af1, b1, acc[nt]);
    }
  }
#pragma unroll
  for (int nt = 0; nt < 4; ++nt) {
#pragma unroll
    for (int r = 0; r < 4; ++r) {
      int m = m0 + w * 16 + lg * 4 + r;
      int n = n0 + nt * 16 + lm;
      if (OUT_BF16)
        ((u16*)C)[(size_t)m * ldc + n] = f2bf(acc[nt][r]);
      else
        ((float*)C)[(size_t)m * ldc + n] = acc[nt][r];
    }
  }
}

// ---------------- fused masked flash attention ----------------
// grid: 512 flat blocks; h = bid&7 (one head per XCD for L2 K/V reuse), qb = bid>>3
__global__ __launch_bounds__(256) void attn_kernel(const u16* __restrict__ Qc,
                                                   const u16* __restrict__ Kc,
                                                   const u16* __restrict__ Vt,
                                                   const unsigned long long* __restrict__ bits,
                                                   u16* __restrict__ Ocat) {
  __shared__ __align__(16) u16 lK[64 * 64];
  __shared__ __align__(16) u16 lV[64 * 64];
  __shared__ __align__(16) u16 lP[4][16 * 64];
  const int bid = blockIdx.x;
  const int h = bid & 7, qb = bid >> 3;
  const int tid = threadIdx.x;
  const int w = tid >> 6, lane = tid & 63, lm = lane & 15, lg = lane >> 4;
  const int qrow = qb * 64 + w * 16 + lm;
  short8 qf0 = *(const short8*)(Qc + (size_t)qrow * DMODEL + h * 64 + lg * 8);
  short8 qf1 = *(const short8*)(Qc + (size_t)qrow * DMODEL + h * 64 + 32 + lg * 8);
  f32x4 of[4] = {};
  float m_run[4] = {-1e29f, -1e29f, -1e29f, -1e29f};
  float l_run[4] = {0.f, 0.f, 0.f, 0.f};
  const int srow = tid >> 2, sc0 = tid & 3;
  for (int kb = 0; kb < 64; ++kb) {
    __syncthreads();
    {
      const short8* gk = (const short8*)(Kc + (size_t)(kb * 64 + srow) * DMODEL + h * 64);
      short8* lk = (short8*)(lK + srow * 64);
      lk[sc0 ^ (srow & 7)] = gk[sc0];
      lk[(sc0 + 4) ^ (srow & 7)] = gk[sc0 + 4];
      const short8* gv = (const short8*)(Vt + ((size_t)h * 64 + srow) * N_NODES + kb * 64);
      short8* lv = (short8*)(lV + srow * 64);
      lv[sc0 ^ (srow & 7)] = gv[sc0];
      lv[(sc0 + 4) ^ (srow & 7)] = gv[sc0 + 4];
    }
    __syncthreads();
    f32x4 s[4] = {};
#pragma unroll
    for (int kt = 0; kt < 4; ++kt) {
      int row = kt * 16 + lm;
      short8 k0 = ((short8*)(lK + row * 64))[lg ^ (row & 7)];
      short8 k1 = ((short8*)(lK + row * 64))[(4 + lg) ^ (row & 7)];
      s[kt] = mfma16(qf0, k0, s[kt]);
      s[kt] = mfma16(qf1, k1, s[kt]);
    }
    // adjacency mask (bit per (q,key)); masked -> -1e30 (exp underflows to 0)
#pragma unroll
    for (int r = 0; r < 4; ++r) {
      unsigned long long wb = bits[(size_t)(qb * 64 + w * 16 + lg * 4 + r) * 64 + kb];
#pragma unroll
      for (int kt = 0; kt < 4; ++kt)
        if (!((wb >> (kt * 16 + lm)) & 1ull)) s[kt][r] = -1e30f;
    }
    // online softmax
    float sc[4];
#pragma unroll
    for (int r = 0; r < 4; ++r) {
      float pm = fmaxf(fmaxf(s[0][r], s[1][r]), fmaxf(s[2][r], s[3][r]));
#pragma unroll
      for (int off = 1; off < 16; off <<= 1) pm = fmaxf(pm, __shfl_xor(pm, off));
      float mnew = fmaxf(m_run[r], pm);
      sc[r] = __expf(m_run[r] - mnew);
      m_run[r] = mnew;
    }
#pragma unroll
    for (int r = 0; r < 4; ++r) {
      float rs = 0.f;
#pragma unroll
      for (int kt = 0; kt < 4; ++kt) {
        s[kt][r] = __expf(s[kt][r] - m_run[r]);
        rs += s[kt][r];
      }
#pragma unroll
      for (int off = 1; off < 16; off <<= 1) rs += __shfl_xor(rs, off);
      l_run[r] = l_run[r] * sc[r] + rs;
    }
#pragma unroll
    for (int dt = 0; dt < 4; ++dt)
#pragma unroll
      for (int r = 0; r < 4; ++r) of[dt][r] *= sc[r];
    // P -> per-wave LDS tile (swizzled), then PV
    u16* Pw = lP[w];
#pragma unroll
    for (int kt = 0; kt < 4; ++kt)
#pragma unroll
      for (int r = 0; r < 4; ++r) {
        int q = lg * 4 + r, col = kt * 16 + lm;
        Pw[q * 64 + (col ^ ((q & 7) << 3))] = f2bf(s[kt][r]);
      }
#pragma unroll
    for (int ks = 0; ks < 2; ++ks) {
      short8 pa = ((short8*)(Pw + lm * 64))[(ks * 4 + lg) ^ (lm & 7)];
#pragma unroll
      for (int dt = 0; dt < 4; ++dt) {
        int row = dt * 16 + lm;
        short8 vb = ((short8*)(lV + row * 64))[(ks * 4 + lg) ^ (row & 7)];
        of[dt] = mfma16(pa, vb, of[dt]);
      }
    }
  }
#pragma unroll
  for (int r = 0; r < 4; ++r) l_run[r] = 1.0f / l_run[r];
#pragma unroll
  for (int dt = 0; dt < 4; ++dt)
#pragma unroll
    for (int r = 0; r < 4; ++r) {
      int q = qb * 64 + w * 16 + lg * 4 + r;
      int col = h * 64 + dt * 16 + lm;
      Ocat[(size_t)q * DMODEL + col] = f2bf(of[dt][r] * l_run[r]);
    }
}

// ---------------- launcher ----------------

extern "C" void kernel_launch(void* const* d_in, const int* in_sizes, int n_in,
                              void* d_out, int out_size, void* d_ws, size_t ws_size,
                              hipStream_t stream) {
  const float* X   = (const float*)d_in[0];
  const float* Adj = (const float*)d_in[1];
  const float* Wks = (const float*)d_in[2];   // note: K before Q in input order
  const float* Wqs = (const float*)d_in[3];
  const float* Wvs = (const float*)d_in[4];
  const float* Wo  = (const float*)d_in[5];

  char* p = (char*)d_ws;
  u16* Xb  = (u16*)p; p += (size_t)N_NODES * DMODEL * 2;
  u16* Wqt = (u16*)p; p += (size_t)DMODEL * DMODEL * 2;
  u16* Wkt = (u16*)p; p += (size_t)DMODEL * DMODEL * 2;
  u16* Wvt = (u16*)p; p += (size_t)DMODEL * DMODEL * 2;
  u16* Wot = (u16*)p; p += (size_t)DMODEL * DMODEL * 2;
  u16* Qc  = (u16*)p; p += (size_t)N_NODES * DMODEL * 2;
  u16* Kc  = (u16*)p; p += (size_t)N_NODES * DMODEL * 2;
  u16* Vc  = (u16*)p; p += (size_t)N_NODES * DMODEL * 2;
  u16* Vt  = (u16*)p; p += (size_t)N_NODES * DMODEL * 2;
  u16* Oc  = (u16*)p; p += (size_t)N_NODES * DMODEL * 2;
  unsigned long long* bits = (unsigned long long*)p; p += (size_t)N_NODES * 64 * 8;

  conv_bf16<<<dim3(2048), dim3(256), 0, stream>>>(X, Xb, N_NODES * DMODEL / 4);
  pack_qkv<<<dim3(8, 1, 24), dim3(256), 0, stream>>>(Wks, Wqs, Wvs, Wkt, Wqt, Wvt);
  pack_wo<<<dim3(8, 8), dim3(256), 0, stream>>>(Wo, Wot);
  build_bits<<<dim3(2048), dim3(256), 0, stream>>>(Adj, bits);

  gemm_nt<true><<<dim3(64, 8), dim3(256), 0, stream>>>(Xb, Wqt, Qc, 512, 512, 512, 512);
  gemm_nt<true><<<dim3(64, 8), dim3(256), 0, stream>>>(Xb, Wkt, Kc, 512, 512, 512, 512);
  gemm_nt<true><<<dim3(64, 8), dim3(256), 0, stream>>>(Xb, Wvt, Vc, 512, 512, 512, 512);
  vtrans<<<dim3(64, 8), dim3(256), 0, stream>>>(Vc, Vt);

  attn_kernel<<<dim3(512), dim3(256), 0, stream>>>(Qc, Kc, Vt, bits, Oc);

  gemm_nt<false><<<dim3(64, 8), dim3(256), 0, stream>>>(Oc, Wot, d_out, 512, 512, 512, 512);
}

// Round 2
// 171.355 us; speedup vs baseline: 1.2522x; 1.2522x over previous
//
#include <hip/hip_runtime.h>
#include <stdint.h>

typedef unsigned short u16;
typedef __attribute__((ext_vector_type(8))) __bf16 bf16x8;
typedef __attribute__((ext_vector_type(8))) short short8;
typedef __attribute__((ext_vector_type(4))) float f32x4;

#define N_NODES 4096
#define DMODEL  512   // 8 heads * 64
#define KD      64
#define NH      8
#define LOG2E   1.4426950408889634f

static __device__ __forceinline__ u16 f2bf(float f) {
  unsigned u = __builtin_bit_cast(unsigned, f);
  u += 0x7fffu + ((u >> 16) & 1u);
  return (u16)(u >> 16);
}

static __device__ __forceinline__ f32x4 mfma16(short8 a, short8 b, f32x4 c) {
  return __builtin_amdgcn_mfma_f32_16x16x32_bf16(
      __builtin_bit_cast(bf16x8, a), __builtin_bit_cast(bf16x8, b), c, 0, 0, 0);
}

static __device__ __forceinline__ void gload16(const u16* g, u16* l) {
  __builtin_amdgcn_global_load_lds((const __attribute__((address_space(1))) void*)g,
                                   (__attribute__((address_space(3))) void*)l, 16, 0, 0);
}

// ---------------- prep kernels ----------------

__global__ void conv_bf16(const float* __restrict__ in, u16* __restrict__ out, int n4) {
  int i = blockIdx.x * blockDim.x + threadIdx.x;
  if (i < n4) {
    float4 v = ((const float4*)in)[i];
    ushort4 o; o.x = f2bf(v.x); o.y = f2bf(v.y); o.z = f2bf(v.z); o.w = f2bf(v.w);
    ((ushort4*)out)[i] = o;
  }
}

// W[h][512][64] -> Wt[h*64+k][512] (transposed per head), optional scale
__global__ void pack_qkv(const float* __restrict__ Wk, const float* __restrict__ Wq,
                         const float* __restrict__ Wv, u16* __restrict__ Wkt,
                         u16* __restrict__ Wqt, u16* __restrict__ Wvt) {
  __shared__ float t[64][65];
  int z = blockIdx.z;            // mat*8 + h
  int mat = z >> 3, h = z & 7;
  const float* src = (mat == 0) ? Wk : ((mat == 1) ? Wq : Wv);
  u16* dst = (mat == 0) ? Wkt : ((mat == 1) ? Wqt : Wvt);
  // fold 1/sqrt(64) AND log2(e) into Q so scores are in exp2 domain
  float scale = (mat == 1) ? 0.125f * LOG2E : 1.0f;
  src += (size_t)h * DMODEL * KD;
  dst += (size_t)h * KD * DMODEL;
  int r0 = blockIdx.x * 64;      // j tile
  int tid = threadIdx.x, lc = tid & 63;
#pragma unroll
  for (int i = 0; i < 16; ++i) {
    int row = i * 4 + (tid >> 6);
    t[row][lc] = src[(size_t)(r0 + row) * KD + lc];
  }
  __syncthreads();
#pragma unroll
  for (int i = 0; i < 16; ++i) {
    int row = i * 4 + (tid >> 6);   // k
    dst[(size_t)row * DMODEL + r0 + lc] = f2bf(t[lc][row] * scale);
  }
}

// Wo[512 c][512 o] -> Wot[o][c]
__global__ void pack_wo(const float* __restrict__ Wo, u16* __restrict__ Wot) {
  __shared__ float t[64][65];
  int r0 = blockIdx.x * 64, c0 = blockIdx.y * 64;
  int tid = threadIdx.x, lc = tid & 63;
#pragma unroll
  for (int i = 0; i < 16; ++i) {
    int row = i * 4 + (tid >> 6);
    t[row][lc] = Wo[(size_t)(r0 + row) * 512 + c0 + lc];
  }
  __syncthreads();
#pragma unroll
  for (int i = 0; i < 16; ++i) {
    int row = i * 4 + (tid >> 6);
    Wot[(size_t)(c0 + row) * 512 + r0 + lc] = f2bf(t[lc][row]);
  }
}

// adjacency (0/1 float, + self loops) -> bit matrix u64[4096][64]
__global__ void build_bits(const float* __restrict__ adj, unsigned long long* __restrict__ bits) {
  int gw = (blockIdx.x * blockDim.x + threadIdx.x) >> 6;
  int lane = threadIdx.x & 63;
  int nw = (gridDim.x * blockDim.x) >> 6;
  for (int word = gw; word < N_NODES * 64; word += nw) {
    int q = word >> 6, wc = word & 63;
    int k = wc * 64 + lane;
    float v = adj[(size_t)q * N_NODES + k];
    unsigned long long m = __ballot((v != 0.0f) || (q == k));
    if (lane == 0) bits[word] = m;
  }
}

// Vc[4096][512] -> Vt[h*64+d][4096]
__global__ void vtrans(const u16* __restrict__ Vc, u16* __restrict__ Vt) {
  __shared__ u16 t[64][65];
  int n0 = blockIdx.x * 64, h = blockIdx.y;
  int tid = threadIdx.x, lc = tid & 63;
#pragma unroll
  for (int i = 0; i < 16; ++i) {
    int row = i * 4 + (tid >> 6);
    t[row][lc] = Vc[(size_t)(n0 + row) * DMODEL + h * 64 + lc];
  }
  __syncthreads();
#pragma unroll
  for (int i = 0; i < 16; ++i) {
    int d = i * 4 + (tid >> 6);
    Vt[((size_t)h * 64 + d) * N_NODES + n0 + lc] = t[lc][d];
  }
}

// ---------------- GEMM: C[M][N] = A[M][K] * Bt[N][K]^T ----------------
template <bool OUT_BF16>
__global__ __launch_bounds__(256) void gemm_nt(const u16* __restrict__ A,
                                               const u16* __restrict__ Bt,
                                               void* __restrict__ C, int K,
                                               int lda, int ldb, int ldc) {
  __shared__ __align__(16) u16 lA[64 * 64];
  __shared__ __align__(16) u16 lB[64 * 64];
  const int m0 = blockIdx.x * 64, n0 = blockIdx.y * 64;
  const int tid = threadIdx.x;
  const int w = tid >> 6, lane = tid & 63, lm = lane & 15, lg = lane >> 4;
  const int srow = tid >> 2, sc0 = tid & 3;
  f32x4 acc[4] = {};
  for (int k0 = 0; k0 < K; k0 += 64) {
    __syncthreads();
    {
      const short8* ga = (const short8*)(A + (size_t)(m0 + srow) * lda + k0);
      short8* la = (short8*)(lA + srow * 64);
      la[sc0 ^ (srow & 7)] = ga[sc0];
      la[(sc0 + 4) ^ (srow & 7)] = ga[sc0 + 4];
      const short8* gb = (const short8*)(Bt + (size_t)(n0 + srow) * ldb + k0);
      short8* lb = (short8*)(lB + srow * 64);
      lb[sc0 ^ (srow & 7)] = gb[sc0];
      lb[(sc0 + 4) ^ (srow & 7)] = gb[sc0 + 4];
    }
    __syncthreads();
    short8 af0, af1;
    {
      int row = w * 16 + lm;
      af0 = ((short8*)(lA + row * 64))[lg ^ (row & 7)];
      af1 = ((short8*)(lA + row * 64))[(4 + lg) ^ (row & 7)];
    }
#pragma unroll
    for (int nt = 0; nt < 4; ++nt) {
      int row = nt * 16 + lm;
      short8 b0 = ((short8*)(lB + row * 64))[lg ^ (row & 7)];
      short8 b1 = ((short8*)(lB + row * 64))[(4 + lg) ^ (row & 7)];
      acc[nt] = mfma16(af0, b0, acc[nt]);
      acc[nt] = mfma16(af1, b1, acc[nt]);
    }
  }
#pragma unroll
  for (int nt = 0; nt < 4; ++nt) {
#pragma unroll
    for (int r = 0; r < 4; ++r) {
      int m = m0 + w * 16 + lg * 4 + r;
      int n = n0 + nt * 16 + lm;
      if (OUT_BF16)
        ((u16*)C)[(size_t)m * ldc + n] = f2bf(acc[nt][r]);
      else
        ((float*)C)[(size_t)m * ldc + n] = acc[nt][r];
    }
  }
}

// ---------------- fused masked flash attention (swapped-operand, in-reg softmax) ---
// grid: 512 flat blocks; h = bid&7 (head -> XCD L2 affinity), qb = bid>>3
__global__ __launch_bounds__(256) void attn_kernel(const u16* __restrict__ Qc,
                                                   const u16* __restrict__ Kc,
                                                   const u16* __restrict__ Vt,
                                                   const unsigned long long* __restrict__ bits,
                                                   u16* __restrict__ Ocat) {
  // double-buffered K/V tiles (linear layout for global_load_lds; source pre-swizzled)
  __shared__ __align__(16) u16 lK[2][64 * 64];
  __shared__ __align__(16) u16 lV[2][64 * 64];
  __shared__ __align__(16) u16 lP[4][16 * 64];   // per-wave P tile
  const int bid = blockIdx.x;
  const int h = bid & 7, qb = bid >> 3;
  const int tid = threadIdx.x;
  const int w = tid >> 6, lane = tid & 63, lm = lane & 15, lg = lane >> 4;

  // Q as B-operand: q = qb*64 + w*16 + lm, d-slices lg*8 and 32+lg*8
  const int qrow = qb * 64 + w * 16 + lm;
  const short8 qf0 = *(const short8*)(Qc + (size_t)qrow * DMODEL + h * 64 + lg * 8);
  const short8 qf1 = *(const short8*)(Qc + (size_t)qrow * DMODEL + h * 64 + 32 + lg * 8);

  // staging: wave w stages rows w*16 .. w*16+15 of the 64-row tile (2 issues of 1KB)
  // LDS dest linear: row = w*16 + i*8 + (lane>>3), chunk c = lane&7 (16B chunks)
  // source column pre-swizzled: chunk c ^ (row&7)  (read side applies same XOR)
  const int srow = lane >> 3, sc = lane & 7;
  const u16* kSrc[2]; const u16* vSrc[2];
#pragma unroll
  for (int i = 0; i < 2; ++i) {
    int row = w * 16 + i * 8 + srow;
    kSrc[i] = Kc + (size_t)row * DMODEL + h * 64 + (sc ^ (row & 7)) * 8;
    vSrc[i] = Vt + ((size_t)h * 64 + row) * N_NODES + (sc ^ (row & 7)) * 8;
  }

#define STAGE(buf, kb) do {                                                   \
    const size_t kOff = (size_t)(kb) * 64 * DMODEL;                           \
    const size_t vOff = (size_t)(kb) * 64;                                    \
    gload16(kSrc[0] + kOff, &lK[buf][(w * 2 + 0) * 512]);                     \
    gload16(kSrc[1] + kOff, &lK[buf][(w * 2 + 1) * 512]);                     \
    gload16(vSrc[0] + vOff, &lV[buf][(w * 2 + 0) * 512]);                     \
    gload16(vSrc[1] + vOff, &lV[buf][(w * 2 + 1) * 512]);                     \
  } while (0)

  f32x4 of[4] = {};
  float m_run = -1e30f, l_run = 0.f;
  const unsigned long long* bp = bits + (size_t)qrow * 64;

  int cur = 0;
  STAGE(0, 0);
  unsigned long long wb = bp[0];

  char* Pw = (char*)lP[w];
  const int pswz = (lm & 7) << 4;

  for (int kb = 0; kb < 64; ++kb) {
    // current tile's loads are the only outstanding ones -> full drain is exact
    asm volatile("s_waitcnt vmcnt(0)" ::: "memory");
    __builtin_amdgcn_s_barrier();
    if (kb + 1 < 64) STAGE(cur ^ 1, kb + 1);
    unsigned long long wb_next = (kb + 1 < 64) ? bp[kb + 1] : 0ull;

    // --- QK^T swapped: s[kt] = K_tile(kt)^ . Q  -> D[key][q], lane: q=lm, key=kt*16+lg*4+r
    const u16* lKc = lK[cur];
    f32x4 s[4];
#pragma unroll
    for (int kt = 0; kt < 4; ++kt) {
      int row = kt * 16 + lm;
      short8 k0 = ((const short8*)(lKc + row * 64))[lg ^ (row & 7)];
      short8 k1 = ((const short8*)(lKc + row * 64))[(4 + lg) ^ (row & 7)];
      f32x4 z = {};
      z = mfma16(k0, qf0, z);
      s[kt] = mfma16(k1, qf1, z);
    }

    // --- per-q max (may include masked scores: still a valid upper bound)
    float pm = fmaxf(fmaxf(fmaxf(s[0][0], s[0][1]), fmaxf(s[0][2], s[0][3])),
                     fmaxf(fmaxf(s[1][0], s[1][1]), fmaxf(s[1][2], s[1][3])));
    pm = fmaxf(pm, fmaxf(fmaxf(fmaxf(s[2][0], s[2][1]), fmaxf(s[2][2], s[2][3])),
                         fmaxf(fmaxf(s[3][0], s[3][1]), fmaxf(s[3][2], s[3][3]))));
    pm = fmaxf(pm, __shfl_xor(pm, 16));
    pm = fmaxf(pm, __shfl_xor(pm, 32));

    // defer-max (THR=8 in exp2 domain -> p <= 256, fine in bf16)
    if (!__all(pm <= m_run + 8.0f)) {
      float mnew = fmaxf(m_run, pm);
      float scl = __builtin_exp2f(m_run - mnew);
      m_run = mnew;
      l_run *= scl;
#pragma unroll
      for (int dt = 0; dt < 4; ++dt) of[dt] = of[dt] * scl;
    }

    // --- exp2, mask-zero, sum, pack to bf16 pairs
    unsigned wlo = (unsigned)(wb >> (lg * 4));
    unsigned whi = (unsigned)(wb >> (lg * 4 + 32));
    float rs = 0.f;
    unsigned pw[4][2];
#pragma unroll
    for (int kt = 0; kt < 4; ++kt) {
      float pv[4];
#pragma unroll
      for (int r = 0; r < 4; ++r) {
        float e = __builtin_exp2f(s[kt][r] - m_run);
        int pos = (kt & 1) * 16 + r;              // kt0,1 -> wlo ; kt2,3 -> whi
        unsigned word = (kt < 2) ? wlo : whi;
        unsigned mb = (unsigned)((int)(word << (31 - pos)) >> 31);  // 0 or ~0
        e = __builtin_bit_cast(float, __builtin_bit_cast(unsigned, e) & mb);
        pv[r] = e;
        rs += e;
      }
      asm("v_cvt_pk_bf16_f32 %0, %1, %2" : "=v"(pw[kt][0]) : "v"(pv[0]), "v"(pv[1]));
      asm("v_cvt_pk_bf16_f32 %0, %1, %2" : "=v"(pw[kt][1]) : "v"(pv[2]), "v"(pv[3]));
    }
    rs += __shfl_xor(rs, 16);
    rs += __shfl_xor(rs, 32);
    l_run += rs;

    // --- P -> per-wave LDS tile: row q=lm, key bytes 2k, XOR-swizzled; b64 writes
#pragma unroll
    for (int kt = 0; kt < 4; ++kt) {
      uint2 pr; pr.x = pw[kt][0]; pr.y = pw[kt][1];
      *(uint2*)(Pw + lm * 128 + ((kt * 32 + lg * 8) ^ pswz)) = pr;
    }
    // B-fragment reads: q-row lm, keys m*32 + lg*8 .. +7
    short8 pa0 = *(const short8*)(Pw + lm * 128 + ((lg * 16) ^ pswz));
    short8 pa1 = *(const short8*)(Pw + lm * 128 + ((64 + lg * 16) ^ pswz));

    // --- PV swapped: of[dt] = V(dt)^ . P -> D[d][q], lane: q=lm, d=dt*16+lg*4+r
    const u16* lVc = lV[cur];
#pragma unroll
    for (int dt = 0; dt < 4; ++dt) {
      int row = dt * 16 + lm;
      short8 v0 = ((const short8*)(lVc + row * 64))[lg ^ (row & 7)];
      short8 v1 = ((const short8*)(lVc + row * 64))[(4 + lg) ^ (row & 7)];
      of[dt] = mfma16(v0, pa0, of[dt]);
      of[dt] = mfma16(v1, pa1, of[dt]);
    }

    wb = wb_next;
    cur ^= 1;
  }
#undef STAGE

  float inv = 1.0f / l_run;
#pragma unroll
  for (int dt = 0; dt < 4; ++dt) {
    ushort4 o4;
#pragma unroll
    for (int r = 0; r < 4; ++r) o4.x = o4.x, ((u16*)&o4)[r] = f2bf(of[dt][r] * inv);
    *(ushort4*)(&Ocat[(size_t)qrow * DMODEL + h * 64 + dt * 16 + lg * 4]) = o4;
  }
}

// ---------------- launcher ----------------

extern "C" void kernel_launch(void* const* d_in, const int* in_sizes, int n_in,
                              void* d_out, int out_size, void* d_ws, size_t ws_size,
                              hipStream_t stream) {
  const float* X   = (const float*)d_in[0];
  const float* Adj = (const float*)d_in[1];
  const float* Wks = (const float*)d_in[2];
  const float* Wqs = (const float*)d_in[3];
  const float* Wvs = (const float*)d_in[4];
  const float* Wo  = (const float*)d_in[5];

  char* p = (char*)d_ws;
  u16* Xb  = (u16*)p; p += (size_t)N_NODES * DMODEL * 2;
  u16* Wqt = (u16*)p; p += (size_t)DMODEL * DMODEL * 2;
  u16* Wkt = (u16*)p; p += (size_t)DMODEL * DMODEL * 2;
  u16* Wvt = (u16*)p; p += (size_t)DMODEL * DMODEL * 2;
  u16* Wot = (u16*)p; p += (size_t)DMODEL * DMODEL * 2;
  u16* Qc  = (u16*)p; p += (size_t)N_NODES * DMODEL * 2;
  u16* Kc  = (u16*)p; p += (size_t)N_NODES * DMODEL * 2;
  u16* Vc  = (u16*)p; p += (size_t)N_NODES * DMODEL * 2;
  u16* Vt  = (u16*)p; p += (size_t)N_NODES * DMODEL * 2;
  u16* Oc  = (u16*)p; p += (size_t)N_NODES * DMODEL * 2;
  unsigned long long* bits = (unsigned long long*)p; p += (size_t)N_NODES * 64 * 8;

  conv_bf16<<<dim3(2048), dim3(256), 0, stream>>>(X, Xb, N_NODES * DMODEL / 4);
  pack_qkv<<<dim3(8, 1, 24), dim3(256), 0, stream>>>(Wks, Wqs, Wvs, Wkt, Wqt, Wvt);
  pack_wo<<<dim3(8, 8), dim3(256), 0, stream>>>(Wo, Wot);
  build_bits<<<dim3(2048), dim3(256), 0, stream>>>(Adj, bits);

  gemm_nt<true><<<dim3(64, 8), dim3(256), 0, stream>>>(Xb, Wqt, Qc, 512, 512, 512, 512);
  gemm_nt<true><<<dim3(64, 8), dim3(256), 0, stream>>>(Xb, Wkt, Kc, 512, 512, 512, 512);
  gemm_nt<true><<<dim3(64, 8), dim3(256), 0, stream>>>(Xb, Wvt, Vc, 512, 512, 512, 512);
  vtrans<<<dim3(64, 8), dim3(256), 0, stream>>>(Vc, Vt);

  attn_kernel<<<dim3(512), dim3(256), 0, stream>>>(Qc, Kc, Vt, bits, Oc);

  gemm_nt<false><<<dim3(64, 8), dim3(256), 0, stream>>>(Oc, Wot, d_out, 512, 512, 512, 512);
}

// Round 3
// 132.774 us; speedup vs baseline: 1.6160x; 1.2906x over previous
//
#include <hip/hip_runtime.h>
#include <stdint.h>

typedef unsigned short u16;
typedef __attribute__((ext_vector_type(8))) __bf16 bf16x8;
typedef __attribute__((ext_vector_type(8))) short short8;
typedef __attribute__((ext_vector_type(4))) float f32x4;

#define N_NODES 4096
#define DMODEL  512   // 8 heads * 64
#define QKVLD   1536  // Q|K|V concatenated per node
#define KD      64
#define NH      8
#define LOG2E   1.4426950408889634f

static __device__ __forceinline__ u16 f2bf(float f) {
  unsigned u = __builtin_bit_cast(unsigned, f);
  u += 0x7fffu + ((u >> 16) & 1u);
  return (u16)(u >> 16);
}

static __device__ __forceinline__ f32x4 mfma16(short8 a, short8 b, f32x4 c) {
  return __builtin_amdgcn_mfma_f32_16x16x32_bf16(
      __builtin_bit_cast(bf16x8, a), __builtin_bit_cast(bf16x8, b), c, 0, 0, 0);
}

static __device__ __forceinline__ void gload16(const u16* g, u16* l) {
  __builtin_amdgcn_global_load_lds((const __attribute__((address_space(1))) void*)g,
                                   (__attribute__((address_space(3))) void*)l, 16, 0, 0);
}

// ---------------- prep kernels ----------------

__global__ void conv_bf16(const float* __restrict__ in, u16* __restrict__ out, int n4) {
  int i = blockIdx.x * blockDim.x + threadIdx.x;
  if (i < n4) {
    float4 v = ((const float4*)in)[i];
    ushort4 o; o.x = f2bf(v.x); o.y = f2bf(v.y); o.z = f2bf(v.z); o.w = f2bf(v.w);
    ((ushort4*)out)[i] = o;
  }
}

// W[h][512][64] -> Wt rows: [mat*512 + h*64 + k][512 j]  (mat 0=Q,1=K,2=V)
__global__ void pack_qkv(const float* __restrict__ Wq, const float* __restrict__ Wk,
                         const float* __restrict__ Wv, u16* __restrict__ Wt) {
  __shared__ float t[64][65];
  int z = blockIdx.z;            // mat*8 + h
  int mat = z >> 3, h = z & 7;
  const float* src = (mat == 0) ? Wq : ((mat == 1) ? Wk : Wv);
  // fold 1/sqrt(64) AND log2(e) into Q so scores are in exp2 domain
  float scale = (mat == 0) ? 0.125f * LOG2E : 1.0f;
  src += (size_t)h * DMODEL * KD;
  u16* dst = Wt + ((size_t)mat * DMODEL + (size_t)h * KD) * DMODEL;
  int r0 = blockIdx.x * 64;      // j tile
  int tid = threadIdx.x, lc = tid & 63;
#pragma unroll
  for (int i = 0; i < 16; ++i) {
    int row = i * 4 + (tid >> 6);
    t[row][lc] = src[(size_t)(r0 + row) * KD + lc];
  }
  __syncthreads();
#pragma unroll
  for (int i = 0; i < 16; ++i) {
    int row = i * 4 + (tid >> 6);   // k
    dst[(size_t)row * DMODEL + r0 + lc] = f2bf(t[lc][row] * scale);
  }
}

// Wo[512 c][512 o] -> Wot[o][c]
__global__ void pack_wo(const float* __restrict__ Wo, u16* __restrict__ Wot) {
  __shared__ float t[64][65];
  int r0 = blockIdx.x * 64, c0 = blockIdx.y * 64;
  int tid = threadIdx.x, lc = tid & 63;
#pragma unroll
  for (int i = 0; i < 16; ++i) {
    int row = i * 4 + (tid >> 6);
    t[row][lc] = Wo[(size_t)(r0 + row) * 512 + c0 + lc];
  }
  __syncthreads();
#pragma unroll
  for (int i = 0; i < 16; ++i) {
    int row = i * 4 + (tid >> 6);
    Wot[(size_t)(c0 + row) * 512 + r0 + lc] = f2bf(t[lc][row]);
  }
}

// adjacency (0/1 float, + self loops) -> bit matrix u64[4096][64]
__global__ void build_bits(const float* __restrict__ adj, unsigned long long* __restrict__ bits) {
  int gw = (blockIdx.x * blockDim.x + threadIdx.x) >> 6;
  int lane = threadIdx.x & 63;
  int nw = (gridDim.x * blockDim.x) >> 6;
  for (int word = gw; word < N_NODES * 64; word += nw) {
    int q = word >> 6, wc = word & 63;
    int k = wc * 64 + lane;
    float v = adj[(size_t)q * N_NODES + k];
    unsigned long long m = __ballot((v != 0.0f) || (q == k));
    if (lane == 0) bits[word] = m;
  }
}

// QKV[:,1024+h*64+d] -> Vt[h*64+d][4096]
__global__ void vtrans(const u16* __restrict__ QKV, u16* __restrict__ Vt) {
  __shared__ u16 t[64][65];
  int n0 = blockIdx.x * 64, h = blockIdx.y;
  int tid = threadIdx.x, lc = tid & 63;
#pragma unroll
  for (int i = 0; i < 16; ++i) {
    int row = i * 4 + (tid >> 6);
    t[row][lc] = QKV[(size_t)(n0 + row) * QKVLD + 1024 + h * 64 + lc];
  }
  __syncthreads();
#pragma unroll
  for (int i = 0; i < 16; ++i) {
    int d = i * 4 + (tid >> 6);
    Vt[((size_t)h * 64 + d) * N_NODES + n0 + lc] = t[lc][d];
  }
}

// ---------------- GEMM: C[M][N] = A[M][K] * Bt[N][K]^T ----------------
template <bool OUT_BF16>
__global__ __launch_bounds__(256) void gemm_nt(const u16* __restrict__ A,
                                               const u16* __restrict__ Bt,
                                               void* __restrict__ C, int K,
                                               int lda, int ldb, int ldc) {
  __shared__ __align__(16) u16 lA[64 * 64];
  __shared__ __align__(16) u16 lB[64 * 64];
  const int m0 = blockIdx.x * 64, n0 = blockIdx.y * 64;
  const int tid = threadIdx.x;
  const int w = tid >> 6, lane = tid & 63, lm = lane & 15, lg = lane >> 4;
  const int srow = tid >> 2, sc0 = tid & 3;
  f32x4 acc[4] = {};
  for (int k0 = 0; k0 < K; k0 += 64) {
    __syncthreads();
    {
      const short8* ga = (const short8*)(A + (size_t)(m0 + srow) * lda + k0);
      short8* la = (short8*)(lA + srow * 64);
      la[sc0 ^ (srow & 7)] = ga[sc0];
      la[(sc0 + 4) ^ (srow & 7)] = ga[sc0 + 4];
      const short8* gb = (const short8*)(Bt + (size_t)(n0 + srow) * ldb + k0);
      short8* lb = (short8*)(lB + srow * 64);
      lb[sc0 ^ (srow & 7)] = gb[sc0];
      lb[(sc0 + 4) ^ (srow & 7)] = gb[sc0 + 4];
    }
    __syncthreads();
    short8 af0, af1;
    {
      int row = w * 16 + lm;
      af0 = ((short8*)(lA + row * 64))[lg ^ (row & 7)];
      af1 = ((short8*)(lA + row * 64))[(4 + lg) ^ (row & 7)];
    }
#pragma unroll
    for (int nt = 0; nt < 4; ++nt) {
      int row = nt * 16 + lm;
      short8 b0 = ((short8*)(lB + row * 64))[lg ^ (row & 7)];
      short8 b1 = ((short8*)(lB + row * 64))[(4 + lg) ^ (row & 7)];
      acc[nt] = mfma16(af0, b0, acc[nt]);
      acc[nt] = mfma16(af1, b1, acc[nt]);
    }
  }
#pragma unroll
  for (int nt = 0; nt < 4; ++nt) {
#pragma unroll
    for (int r = 0; r < 4; ++r) {
      int m = m0 + w * 16 + lg * 4 + r;
      int n = n0 + nt * 16 + lm;
      if (OUT_BF16)
        ((u16*)C)[(size_t)m * ldc + n] = f2bf(acc[nt][r]);
      else
        ((float*)C)[(size_t)m * ldc + n] = acc[nt][r];
    }
  }
}

// ---------------- fused masked attention, no-max exp2, 2 q-streams, split-K ----
// grid 512: h = bid&7, split s = (bid>>3)&1, qb = bid>>4 (128 q rows / block)
__global__ __launch_bounds__(256, 2) void attn_kernel(const u16* __restrict__ QKV,
                                                      const u16* __restrict__ Vt,
                                                      const unsigned long long* __restrict__ bits,
                                                      float* __restrict__ Op,
                                                      float* __restrict__ lp) {
  __shared__ __align__(16) u16 lK[2][64 * 64];
  __shared__ __align__(16) u16 lV[2][64 * 64];
  __shared__ __align__(16) u16 lP[4][2][16 * 64];
  const int bid = blockIdx.x;
  const int h = bid & 7, sp = (bid >> 3) & 1, qb = bid >> 4;
  const int tid = threadIdx.x;
  const int w = tid >> 6, lane = tid & 63, lm = lane & 15, lg = lane >> 4;
  const int lg4 = lg * 4;
  const int kb0 = sp * 32;                 // this block handles key blocks kb0..kb0+31

  const int q0 = qb * 128 + w * 32 + lm;   // stream 0 q row
  const int q1 = q0 + 16;                  // stream 1 q row

  // Q fragments (B-operand), scores already in exp2 domain (scale folded into Wq)
  const short8 qf00 = *(const short8*)(QKV + (size_t)q0 * QKVLD + h * 64 + lg * 8);
  const short8 qf01 = *(const short8*)(QKV + (size_t)q0 * QKVLD + h * 64 + 32 + lg * 8);
  const short8 qf10 = *(const short8*)(QKV + (size_t)q1 * QKVLD + h * 64 + lg * 8);
  const short8 qf11 = *(const short8*)(QKV + (size_t)q1 * QKVLD + h * 64 + 32 + lg * 8);

  // ones A-fragment for the l row-sum MFMA
  short8 ones;
#pragma unroll
  for (int j = 0; j < 8; ++j) ones[j] = (short)0x3F80;

  // staging pointers: wave w stages rows w*16..+15 of the 64-row tile; pre-swizzled source
  const int srow = lane >> 3, sc = lane & 7;
  const u16* kP[2]; const u16* vP[2];
#pragma unroll
  for (int i = 0; i < 2; ++i) {
    int row = w * 16 + i * 8 + srow;
    kP[i] = QKV + (size_t)(kb0 * 64 + row) * QKVLD + 512 + h * 64 + (sc ^ (row & 7)) * 8;
    vP[i] = Vt + ((size_t)h * 64 + row) * N_NODES + kb0 * 64 + (sc ^ (row & 7)) * 8;
  }

#define STAGE(buf) do {                                   \
    gload16(kP[0], &lK[buf][(w * 2 + 0) * 512]);          \
    gload16(kP[1], &lK[buf][(w * 2 + 1) * 512]);          \
    gload16(vP[0], &lV[buf][(w * 2 + 0) * 512]);          \
    gload16(vP[1], &lV[buf][(w * 2 + 1) * 512]);          \
  } while (0)
#define ADV() do { kP[0] += 64 * QKVLD; kP[1] += 64 * QKVLD; vP[0] += 64; vP[1] += 64; } while (0)

  f32x4 of0[4] = {}, of1[4] = {};
  f32x4 la0 = {}, la1 = {};
  const unsigned long long* bp0 = bits + (size_t)q0 * 64 + kb0;
  const unsigned long long* bp1 = bits + (size_t)q1 * 64 + kb0;

  STAGE(0);
  unsigned long long wb0 = bp0[0], wb1 = bp1[0];

  char* Pw0 = (char*)lP[w][0];
  char* Pw1 = (char*)lP[w][1];
  const int pswz = (lm & 7) << 4;

#define SMPACK(sv, wbv, Pw, la)                                                \
  do {                                                                         \
    unsigned wlo = (unsigned)((wbv) >> lg4);                                   \
    unsigned whi = (unsigned)((wbv) >> (lg4 + 32));                            \
    _Pragma("unroll")                                                          \
    for (int kt = 0; kt < 4; ++kt) {                                           \
      float pv[4];                                                             \
      unsigned word = (kt < 2) ? wlo : whi;                                    \
      _Pragma("unroll")                                                        \
      for (int r = 0; r < 4; ++r) {                                            \
        float e = __builtin_exp2f(sv[kt][r]);                                  \
        int pos = (kt & 1) * 16 + r;                                           \
        unsigned mb = (unsigned)((int)(word << (31 - pos)) >> 31);             \
        pv[r] = __builtin_bit_cast(float, __builtin_bit_cast(unsigned, e) & mb); \
      }                                                                        \
      unsigned pk0, pk1;                                                       \
      asm("v_cvt_pk_bf16_f32 %0, %1, %2" : "=v"(pk0) : "v"(pv[0]), "v"(pv[1]));\
      asm("v_cvt_pk_bf16_f32 %0, %1, %2" : "=v"(pk1) : "v"(pv[2]), "v"(pv[3]));\
      uint2 pr; pr.x = pk0; pr.y = pk1;                                        \
      *(uint2*)(Pw + lm * 128 + ((kt * 32 + lg * 8) ^ pswz)) = pr;             \
    }                                                                          \
    short8 pa0 = *(const short8*)(Pw + lm * 128 + ((lg * 16) ^ pswz));         \
    short8 pa1 = *(const short8*)(Pw + lm * 128 + ((64 + lg * 16) ^ pswz));    \
    la = mfma16(ones, pa0, la);                                                \
    la = mfma16(ones, pa1, la);                                                \
    _Pragma("unroll")                                                          \
    for (int dt = 0; dt < 4; ++dt) {                                           \
      int row = dt * 16 + lm;                                                  \
      short8 v0 = ((const short8*)(lVc + row * 64))[lg ^ (row & 7)];           \
      short8 v1 = ((const short8*)(lVc + row * 64))[(4 + lg) ^ (row & 7)];     \
      OFA[dt] = mfma16(v0, pa0, OFA[dt]);                                      \
      OFA[dt] = mfma16(v1, pa1, OFA[dt]);                                      \
    }                                                                          \
  } while (0)

#define BODY(cur, i)                                                           \
  do {                                                                         \
    asm volatile("s_waitcnt vmcnt(0)" ::: "memory");                           \
    __builtin_amdgcn_s_barrier();                                              \
    if ((i) + 1 < 32) { ADV(); STAGE(cur ^ 1); }                               \
    unsigned long long nb0 = ((i) + 1 < 32) ? bp0[(i) + 1] : 0ull;             \
    unsigned long long nb1 = ((i) + 1 < 32) ? bp1[(i) + 1] : 0ull;             \
    const u16* lKc = lK[cur];                                                  \
    const u16* lVc = lV[cur];                                                  \
    f32x4 s0[4], s1[4];                                                        \
    _Pragma("unroll")                                                          \
    for (int kt = 0; kt < 4; ++kt) {                                           \
      int row = kt * 16 + lm;                                                  \
      short8 k0 = ((const short8*)(lKc + row * 64))[lg ^ (row & 7)];           \
      short8 k1 = ((const short8*)(lKc + row * 64))[(4 + lg) ^ (row & 7)];     \
      f32x4 z0 = {0.f, 0.f, 0.f, 0.f}, z1 = {0.f, 0.f, 0.f, 0.f};              \
      z0 = mfma16(k0, qf00, z0); s0[kt] = mfma16(k1, qf01, z0);                \
      z1 = mfma16(k0, qf10, z1); s1[kt] = mfma16(k1, qf11, z1);                \
    }                                                                          \
    { f32x4* OFA = of0; SMPACK(s0, wb0, Pw0, la0); }                           \
    { f32x4* OFA = of1; SMPACK(s1, wb1, Pw1, la1); }                           \
    wb0 = nb0; wb1 = nb1;                                                      \
  } while (0)

#pragma unroll 1
  for (int it = 0; it < 16; ++it) {
    BODY(0, it * 2);
    BODY(1, it * 2 + 1);
  }
#undef BODY
#undef SMPACK
#undef STAGE
#undef ADV

  // partial outputs (unnormalized) + partial l
  float* Ob = Op + (size_t)sp * N_NODES * DMODEL;
#pragma unroll
  for (int dt = 0; dt < 4; ++dt) {
    *(f32x4*)(Ob + (size_t)q0 * DMODEL + h * 64 + dt * 16 + lg4) = of0[dt];
    *(f32x4*)(Ob + (size_t)q1 * DMODEL + h * 64 + dt * 16 + lg4) = of1[dt];
  }
  if (lg == 0) {
    lp[((size_t)sp * NH + h) * N_NODES + q0] = la0[0];
    lp[((size_t)sp * NH + h) * N_NODES + q1] = la1[0];
  }
}

// combine: Oc[q][hd] = bf16( (Op0+Op1)[q][hd] / (l0+l1)[h][q] )
__global__ __launch_bounds__(256) void combine_kernel(const float* __restrict__ Op,
                                                      const float* __restrict__ lp,
                                                      u16* __restrict__ Oc) {
  int i = blockIdx.x * 256 + threadIdx.x;      // one float4 per thread
  int col = (i * 4) & (DMODEL - 1);
  int q = (i * 4) >> 9;
  int h = col >> 6;
  float4 a = ((const float4*)Op)[i];
  float4 b = ((const float4*)(Op + (size_t)N_NODES * DMODEL))[i];
  float l = lp[(size_t)h * N_NODES + q] + lp[((size_t)NH + h) * N_NODES + q];
  float inv = 1.0f / l;
  ushort4 o;
  o.x = f2bf((a.x + b.x) * inv);
  o.y = f2bf((a.y + b.y) * inv);
  o.z = f2bf((a.z + b.z) * inv);
  o.w = f2bf((a.w + b.w) * inv);
  ((ushort4*)Oc)[i] = o;
}

// ---------------- launcher ----------------

extern "C" void kernel_launch(void* const* d_in, const int* in_sizes, int n_in,
                              void* d_out, int out_size, void* d_ws, size_t ws_size,
                              hipStream_t stream) {
  const float* X   = (const float*)d_in[0];
  const float* Adj = (const float*)d_in[1];
  const float* Wks = (const float*)d_in[2];
  const float* Wqs = (const float*)d_in[3];
  const float* Wvs = (const float*)d_in[4];
  const float* Wo  = (const float*)d_in[5];

  char* p = (char*)d_ws;
  u16* Xb  = (u16*)p; p += (size_t)N_NODES * DMODEL * 2;
  u16* Wt  = (u16*)p; p += (size_t)3 * DMODEL * DMODEL * 2;   // Wq^T|Wk^T|Wv^T stacked
  u16* Wot = (u16*)p; p += (size_t)DMODEL * DMODEL * 2;
  u16* QKV = (u16*)p; p += (size_t)N_NODES * QKVLD * 2;
  u16* Vt  = (u16*)p; p += (size_t)N_NODES * DMODEL * 2;
  u16* Oc  = (u16*)p; p += (size_t)N_NODES * DMODEL * 2;
  unsigned long long* bits = (unsigned long long*)p; p += (size_t)N_NODES * 64 * 8;
  float* Op = (float*)p; p += (size_t)2 * N_NODES * DMODEL * 4;
  float* lp = (float*)p; p += (size_t)2 * NH * N_NODES * 4;

  conv_bf16<<<dim3(2048), dim3(256), 0, stream>>>(X, Xb, N_NODES * DMODEL / 4);
  pack_qkv<<<dim3(8, 1, 24), dim3(256), 0, stream>>>(Wqs, Wks, Wvs, Wt);
  pack_wo<<<dim3(8, 8), dim3(256), 0, stream>>>(Wo, Wot);
  build_bits<<<dim3(2048), dim3(256), 0, stream>>>(Adj, bits);

  // fused Q|K|V projection: C[4096][1536]
  gemm_nt<true><<<dim3(64, 24), dim3(256), 0, stream>>>(Xb, Wt, QKV, 512, 512, 512, QKVLD);
  vtrans<<<dim3(64, 8), dim3(256), 0, stream>>>(QKV, Vt);

  attn_kernel<<<dim3(512), dim3(256), 0, stream>>>(QKV, Vt, bits, Op, lp);
  combine_kernel<<<dim3(N_NODES * DMODEL / 4 / 256), dim3(256), 0, stream>>>(Op, lp, Oc);

  gemm_nt<false><<<dim3(64, 8), dim3(256), 0, stream>>>(Oc, Wot, d_out, 512, 512, 512, 512);
}